// Round 6
// baseline (719.870 us; speedup 1.0000x reference)
//
#include <hip/hip_runtime.h>
#include <stdint.h>

#define DEVI __device__ __forceinline__

typedef __attribute__((ext_vector_type(8))) short bf16x8;   // 8 bf16 (4 VGPRs)
typedef __attribute__((ext_vector_type(4))) float f32x4;    // MFMA C/D

static constexpr int D = 4096;    // d_in == d_out == K == N
static constexpr int M = 16384;   // bs*seq rows

// exact RNE float -> bf16 bits
DEVI unsigned short f2bf(float f) {
  union { float f; unsigned u; } a; a.f = f;
  unsigned r = a.u + 0x7fffu + ((a.u >> 16) & 1u);
  return (unsigned short)(r >> 16);
}

// async global->LDS, 16B per lane; LDS dest is wave-uniform base + lane*16
DEVI void gload_lds16(const void* g, void* l) {
  __builtin_amdgcn_global_load_lds(
      (__attribute__((address_space(1))) void*)(uintptr_t)g,
      (__attribute__((address_space(3))) void*)l,
      16, 0, 0);
}

DEVI f32x4 MFMA(bf16x8 a, bf16x8 b, f32x4 c) {
  return __builtin_amdgcn_mfma_f32_16x16x32_bf16(a, b, c, 0, 0, 0);
}

#define ASM_BAR()    asm volatile("s_barrier" ::: "memory")
#define WAIT_LGKM(N) asm volatile("s_waitcnt lgkmcnt(" #N ")" ::: "memory")
#define WAIT_VM(N)   asm volatile("s_waitcnt vmcnt(" #N ")" ::: "memory")

// ---------------- Kernel A: w_norm (double) + W -> bf16 ----------------
__global__ __launch_bounds__(256) void k_wnorm(const float* __restrict__ w,
                                               double* __restrict__ wn_d,
                                               unsigned short* __restrict__ wbf) {
  const int col = blockIdx.x * 256 + threadIdx.x;
  const int r0 = blockIdx.y * 256;
  double s = 0.0;
  for (int r = r0; r < r0 + 256; ++r) {
    float v = w[(size_t)r * D + col];
    wbf[(size_t)r * D + col] = f2bf(v);
    s += (double)v * (double)v;
  }
  atomicAdd(&wn_d[col], s);
}

__global__ void k_wnf(const double* __restrict__ wn_d, float* __restrict__ wn_f) {
  int i = blockIdx.x * blockDim.x + threadIdx.x;
  if (i < D) wn_f[i] = (float)wn_d[i];
}

// ---------------- Kernel B: 2:4 prune + variance-correct, -> bf16 -------
__global__ __launch_bounds__(256) void k_prune(const float* __restrict__ x,
                                               const float* __restrict__ wn_f,
                                               unsigned short* __restrict__ xs) {
  const int row = blockIdx.x;
  const float* xr = x + (size_t)row * D;
  unsigned short* xo = xs + (size_t)row * D;
  const int t = threadIdx.x;

  float kept[4][4];
  float sx = 0.f, sxx = 0.f, ss = 0.f, sss = 0.f;

#pragma unroll
  for (int i = 0; i < 4; ++i) {
    const int g = t + i * 256;
    const float4 v  = *(const float4*)(xr + 4 * (size_t)g);
    const float4 wv = *(const float4*)(wn_f + 4 * (size_t)g);
    float xv[4] = {v.x, v.y, v.z, v.w};
    float m[4]  = {fabsf(v.x) * wv.x, fabsf(v.y) * wv.y,
                   fabsf(v.z) * wv.z, fabsf(v.w) * wv.w};
    int i1 = 0;
#pragma unroll
    for (int j = 1; j < 4; ++j) if (m[j] > m[i1]) i1 = j;
    int i2 = (i1 == 0) ? 1 : 0;
#pragma unroll
    for (int j = 0; j < 4; ++j) if (j != i1 && j != i2 && m[j] > m[i2]) i2 = j;
#pragma unroll
    for (int j = 0; j < 4; ++j) {
      bool keep = (j == i1) || (j == i2);
      float kv = keep ? xv[j] : 0.f;
      kept[i][j] = kv;
      sx += xv[j]; sxx += xv[j] * xv[j]; ss += kv; sss += kv * kv;
    }
  }

#pragma unroll
  for (int o = 32; o > 0; o >>= 1) {
    sx  += __shfl_down(sx, o);
    sxx += __shfl_down(sxx, o);
    ss  += __shfl_down(ss, o);
    sss += __shfl_down(sss, o);
  }
  __shared__ float wp[4][4];
  __shared__ float s_scale;
  const int wid = t >> 6, lane = t & 63;
  if (lane == 0) { wp[wid][0] = sx; wp[wid][1] = sxx; wp[wid][2] = ss; wp[wid][3] = sss; }
  __syncthreads();
  if (t == 0) {
    float SX = 0, SXX = 0, SS = 0, SSS = 0;
    for (int u = 0; u < 4; ++u) { SX += wp[u][0]; SXX += wp[u][1]; SS += wp[u][2]; SSS += wp[u][3]; }
    float vx = SXX - SX * SX * (1.f / 4096.f);
    float vs = SSS - SS * SS * (1.f / 4096.f);
    s_scale = sqrtf(vx / vs);
  }
  __syncthreads();
  const float sc = s_scale;

#pragma unroll
  for (int i = 0; i < 4; ++i) {
    const int g = t + i * 256;
    ushort4 o;
    o.x = f2bf(kept[i][0] * sc);
    o.y = f2bf(kept[i][1] * sc);
    o.z = f2bf(kept[i][2] * sc);
    o.w = f2bf(kept[i][3] * sc);
    *(ushort4*)(xo + 4 * (size_t)g) = o;
  }
}

// ---------------- Kernel C: bf16 GEMM, 256x256 tile, 4 waves x 128x128 ----
// C[m][n] = sum_k A[m][k]*B[n][k].  BK=32; 3-deep circular LDS regions
// (256x32 bf16 = 16KB): A regions at 0, B at 49152. 4 waves in 2x2 grid,
// each owns a 128x128 output (8x8 16x16x32 frags) -> LDS reads drop to
// 64 b128/step (vs 96 with 8 waves): LDS pipe (~1030cy) < MFMA pipe
// (~1241cy) so overlap can hide reads. Per substep: vmcnt(8) publishes
// region rp; barrier; lgkmcnt(0) retires LAST substep's 16 reads (free);
// issue 16 reads for next substep; 64 MFMA under setprio; stage region sp
// (k for t+3, clamped tail). 1 wave/SIMD; acc 256 AGPR + ~150 VGPR.
__global__ __launch_bounds__(256, 1) void k_gemm(const unsigned short* __restrict__ A,  // [M,K]
                                                 const unsigned short* __restrict__ B,  // [N,K]
                                                 float* __restrict__ C) {               // [M,N]
  extern __shared__ char smem[];   // 98304 bytes

  const int tid  = threadIdx.x;
  const int lane = tid & 63;
  const int wid  = tid >> 6;
  const int wrow = wid >> 1;   // 0..1
  const int wcol = wid & 1;    // 0..1

  // T1: XCD swizzle (1024 blocks, divisible by 8)
  const int bid = blockIdx.x;
  const int swz = (bid & 7) * 128 + (bid >> 3);
  const int m0 = (swz >> 4) * 256;   // 64 row tiles
  const int n0 = (swz & 15) * 256;   // 16 col tiles

  // staging: region = 256 rows x 32 k (row-major, 4x16B chunks per 64B row).
  // 256 threads x 16B -> 4 gloads per matrix per region (g=0..3 -> rows g*64+).
  // Physical chunk lc at row r holds logical chunk lc^((r>>1)&3): pre-swizzle
  // the GLOBAL source k-offset, keep LDS dest linear (rule #21).
  const int r0 = tid >> 2;                                   // 0..63
  const int ksrc = ((tid & 3) ^ ((tid >> 3) & 3)) * 8;       // swizzled k-elems
  const unsigned short* Ar = A + (size_t)(m0 + r0) * D + ksrc;
  const unsigned short* Br = B + (size_t)(n0 + r0) * D + ksrc;
  char* ldst = smem + tid * 16;

  // frag-read byte offsets within a region: row*64 + physical chunk*16,
  // physical chunk = (lane>>4) ^ ((row>>1)&3); row base multiple of 16 so
  // (row>>1)&3 == ((lane&15)>>1)&3 == (lane>>1)&3.
  const int swz16 = (((lane >> 4) ^ ((lane >> 1) & 3)) << 4);
  const int aRd = (wrow * 128 + (lane & 15)) * 64 + swz16;   // + fm*1024 + region
  const int bRd = (wcol * 128 + (lane & 15)) * 64 + swz16;   // + fn*1024 + region

#define STAGE(p, kt) do {                                                  \
    const int _ab = (p) * 16384;                                           \
    const int _bb = 49152 + (p) * 16384;                                   \
    const int _ko = (kt) * 32;                                             \
    _Pragma("unroll")                                                      \
    for (int g = 0; g < 4; ++g)                                            \
      gload_lds16(Ar + (size_t)g * 64 * D + _ko, ldst + _ab + g * 4096);   \
    _Pragma("unroll")                                                      \
    for (int g = 0; g < 4; ++g)                                            \
      gload_lds16(Br + (size_t)g * 64 * D + _ko, ldst + _bb + g * 4096);   \
  } while (0)

#define READ16(xa, xb, rbase) do {                                         \
    _Pragma("unroll")                                                      \
    for (int fm = 0; fm < 8; ++fm)                                         \
      xa[fm] = *(const bf16x8*)(smem + (rbase) * 16384 + aRd + fm * 1024); \
    _Pragma("unroll")                                                      \
    for (int fn = 0; fn < 8; ++fn)                                         \
      xb[fn] = *(const bf16x8*)(smem + 49152 + (rbase) * 16384 + bRd + fn * 1024); \
  } while (0)

#define MFMA64(xa, xb) do {                                                \
    __builtin_amdgcn_s_setprio(1);                                         \
    _Pragma("unroll")                                                      \
    for (int fm = 0; fm < 8; ++fm)                                         \
      _Pragma("unroll")                                                    \
      for (int fn = 0; fn < 8; ++fn)                                       \
        acc[fm][fn] = MFMA(xa[fm], xb[fn], acc[fm][fn]);                   \
    __builtin_amdgcn_s_setprio(0);                                         \
  } while (0)

// one K-step: lgkm(0) retires last substep's reads (already complete);
// read next substep's operands; MFMA on current; stage region sp (k t+3)
#define SUBSTEP(cxa, cxb, nxa, nxb) do {                                   \
    WAIT_VM(8);                       /* publish region rp's stage */      \
    ASM_BAR();                                                             \
    WAIT_LGKM(0);                     /* retire prev reads - free */       \
    READ16(nxa, nxb, rp);                                                  \
    __builtin_amdgcn_sched_barrier(0);                                     \
    MFMA64(cxa, cxb);                                                      \
    __builtin_amdgcn_sched_barrier(0);                                     \
    STAGE(sp, kst);                                                        \
    rp = (rp == 2) ? 0 : rp + 1;                                           \
    sp = (sp == 2) ? 0 : sp + 1;                                           \
    kst = (kst < 127) ? kst + 1 : 127;                                     \
  } while (0)

  f32x4 acc[8][8] = {};
  bf16x8 ca[8], na[8];
  bf16x8 cb[8], nb[8];

  // ---- prologue: stage k0,k1,k2 into regions 0,1,2; read step-0 operands
  STAGE(0, 0);
  STAGE(1, 1);
  STAGE(2, 2);
  WAIT_VM(16);         // region 0 retired
  ASM_BAR();
  READ16(ca, cb, 0);

  int rp = 1, sp = 0, kst = 3;
  for (int d = 0; d < 64; ++d) {
    SUBSTEP(ca, cb, na, nb);
    SUBSTEP(na, nb, ca, cb);
  }
#undef SUBSTEP
#undef MFMA64
#undef READ16
#undef STAGE

  // ---- epilogue: C/D layout col=lane&15, row=(lane>>4)*4+i ----
  const int orow = (lane >> 4) * 4;
  const int ocol = lane & 15;
  float* Cw = C + (size_t)(m0 + wrow * 128 + orow) * D + n0 + wcol * 128 + ocol;
#pragma unroll
  for (int fm = 0; fm < 8; ++fm)
#pragma unroll
    for (int fn = 0; fn < 8; ++fn)
#pragma unroll
      for (int i = 0; i < 4; ++i)
        Cw[(size_t)(fm * 16 + i) * D + fn * 16] = acc[fm][fn][i];
}

extern "C" void kernel_launch(void* const* d_in, const int* in_sizes, int n_in,
                              void* d_out, int out_size, void* d_ws, size_t ws_size,
                              hipStream_t stream) {
  const float* x = (const float*)d_in[0];   // [4,4096,4096] fp32
  const float* w = (const float*)d_in[1];   // [4096,4096] fp32
  float* out = (float*)d_out;               // [16384,4096] fp32

  char* ws = (char*)d_ws;
  double* wn_d = (double*)ws;                                   // 32 KB
  float* wn_f = (float*)(ws + 32768);                           // 16 KB
  unsigned short* wbf = (unsigned short*)(ws + 49152);          // 33.5 MB
  unsigned short* xsb = (unsigned short*)(ws + 49152 + (size_t)D * D * 2);  // 134 MB

  hipMemsetAsync(wn_d, 0, D * sizeof(double), stream);
  k_wnorm<<<dim3(16, 16), 256, 0, stream>>>(w, wn_d, wbf);
  k_wnf<<<16, 256, 0, stream>>>(wn_d, wn_f);
  k_prune<<<M, 256, 0, stream>>>(x, wn_f, xsb);
  k_gemm<<<dim3((M / 256) * (D / 256)), 256, 98304, stream>>>(xsb, wbf, out);
}

// Round 7
// 621.688 us; speedup vs baseline: 1.1579x; 1.1579x over previous
//
#include <hip/hip_runtime.h>
#include <stdint.h>

#define DEVI __device__ __forceinline__

typedef __attribute__((ext_vector_type(8))) short bf16x8;   // 8 bf16 (4 VGPRs)
typedef __attribute__((ext_vector_type(4))) float f32x4;    // MFMA C/D

static constexpr int D = 4096;    // d_in == d_out == K == N
static constexpr int M = 16384;   // bs*seq rows

// exact RNE float -> bf16 bits
DEVI unsigned short f2bf(float f) {
  union { float f; unsigned u; } a; a.f = f;
  unsigned r = a.u + 0x7fffu + ((a.u >> 16) & 1u);
  return (unsigned short)(r >> 16);
}

// async global->LDS, 16B per lane; LDS dest is wave-uniform base + lane*16
DEVI void gload_lds16(const void* g, void* l) {
  __builtin_amdgcn_global_load_lds(
      (__attribute__((address_space(1))) void*)(uintptr_t)g,
      (__attribute__((address_space(3))) void*)l,
      16, 0, 0);
}

DEVI f32x4 MFMA(bf16x8 a, bf16x8 b, f32x4 c) {
  return __builtin_amdgcn_mfma_f32_16x16x32_bf16(a, b, c, 0, 0, 0);
}

#define ASM_BAR()    asm volatile("s_barrier" ::: "memory")
#define WAIT_VM(N)   asm volatile("s_waitcnt vmcnt(" #N ")" ::: "memory")
#define SGB          __builtin_amdgcn_sched_group_barrier

// ---------------- Kernel A: w_norm (double) + W -> bf16 ----------------
__global__ __launch_bounds__(256) void k_wnorm(const float* __restrict__ w,
                                               double* __restrict__ wn_d,
                                               unsigned short* __restrict__ wbf) {
  const int col = blockIdx.x * 256 + threadIdx.x;
  const int r0 = blockIdx.y * 256;
  double s = 0.0;
  for (int r = r0; r < r0 + 256; ++r) {
    float v = w[(size_t)r * D + col];
    wbf[(size_t)r * D + col] = f2bf(v);
    s += (double)v * (double)v;
  }
  atomicAdd(&wn_d[col], s);
}

__global__ void k_wnf(const double* __restrict__ wn_d, float* __restrict__ wn_f) {
  int i = blockIdx.x * blockDim.x + threadIdx.x;
  if (i < D) wn_f[i] = (float)wn_d[i];
}

// ---------------- Kernel B: 2:4 prune + variance-correct, -> bf16 -------
__global__ __launch_bounds__(256) void k_prune(const float* __restrict__ x,
                                               const float* __restrict__ wn_f,
                                               unsigned short* __restrict__ xs) {
  const int row = blockIdx.x;
  const float* xr = x + (size_t)row * D;
  unsigned short* xo = xs + (size_t)row * D;
  const int t = threadIdx.x;

  float kept[4][4];
  float sx = 0.f, sxx = 0.f, ss = 0.f, sss = 0.f;

#pragma unroll
  for (int i = 0; i < 4; ++i) {
    const int g = t + i * 256;
    const float4 v  = *(const float4*)(xr + 4 * (size_t)g);
    const float4 wv = *(const float4*)(wn_f + 4 * (size_t)g);
    float xv[4] = {v.x, v.y, v.z, v.w};
    float m[4]  = {fabsf(v.x) * wv.x, fabsf(v.y) * wv.y,
                   fabsf(v.z) * wv.z, fabsf(v.w) * wv.w};
    int i1 = 0;
#pragma unroll
    for (int j = 1; j < 4; ++j) if (m[j] > m[i1]) i1 = j;
    int i2 = (i1 == 0) ? 1 : 0;
#pragma unroll
    for (int j = 0; j < 4; ++j) if (j != i1 && j != i2 && m[j] > m[i2]) i2 = j;
#pragma unroll
    for (int j = 0; j < 4; ++j) {
      bool keep = (j == i1) || (j == i2);
      float kv = keep ? xv[j] : 0.f;
      kept[i][j] = kv;
      sx += xv[j]; sxx += xv[j] * xv[j]; ss += kv; sss += kv * kv;
    }
  }

#pragma unroll
  for (int o = 32; o > 0; o >>= 1) {
    sx  += __shfl_down(sx, o);
    sxx += __shfl_down(sxx, o);
    ss  += __shfl_down(ss, o);
    sss += __shfl_down(sss, o);
  }
  __shared__ float wp[4][4];
  __shared__ float s_scale;
  const int wid = t >> 6, lane = t & 63;
  if (lane == 0) { wp[wid][0] = sx; wp[wid][1] = sxx; wp[wid][2] = ss; wp[wid][3] = sss; }
  __syncthreads();
  if (t == 0) {
    float SX = 0, SXX = 0, SS = 0, SSS = 0;
    for (int u = 0; u < 4; ++u) { SX += wp[u][0]; SXX += wp[u][1]; SS += wp[u][2]; SSS += wp[u][3]; }
    float vx = SXX - SX * SX * (1.f / 4096.f);
    float vs = SSS - SS * SS * (1.f / 4096.f);
    s_scale = sqrtf(vx / vs);
  }
  __syncthreads();
  const float sc = s_scale;

#pragma unroll
  for (int i = 0; i < 4; ++i) {
    const int g = t + i * 256;
    ushort4 o;
    o.x = f2bf(kept[i][0] * sc);
    o.y = f2bf(kept[i][1] * sc);
    o.z = f2bf(kept[i][2] * sc);
    o.w = f2bf(kept[i][3] * sc);
    *(ushort4*)(xo + 4 * (size_t)g) = o;
  }
}

// ---------------- Kernel C: bf16 GEMM, 256x256 tile, SGB-interleaved ----
// C[m][n] = sum_k A[m][k]*B[n][k].  BK=32; 3-deep circular LDS regions
// (256x32 bf16 = 16KB): A at 0, B at 49152. 8 waves 2x4, 128x64/wave.
// Per step: vmcnt(4)+barrier publish region rp; then ONE scheduling region
// containing 12 ds_read (next step's operands), 32 MFMA (current operands,
// compiler inserts counted lgkmcnt), 4 global_load_lds (k for t+3);
// sched_group_barrier interleaves {1 DS_READ, 2 MFMA}x12 {1 VMEM, 2 MFMA}x4
// so the LDS queue never saturates and issue never backpressures —
// reads/stages flow UNDER the MFMA cluster instead of bursting before it.
__global__ __launch_bounds__(512, 2) void k_gemm(const unsigned short* __restrict__ A,  // [M,K]
                                                 const unsigned short* __restrict__ B,  // [N,K]
                                                 float* __restrict__ C) {               // [M,N]
  extern __shared__ char smem[];   // 98304 bytes

  const int tid  = threadIdx.x;
  const int lane = tid & 63;
  const int wid  = tid >> 6;
  const int wr   = wid >> 2;   // 0..1  (row half)
  const int wc   = wid & 3;    // 0..3  (col quarter)

  // T1: XCD swizzle (1024 blocks, divisible by 8)
  const int bid = blockIdx.x;
  const int swz = (bid & 7) * 128 + (bid >> 3);
  const int m0 = (swz >> 4) * 256;   // 64 row tiles
  const int n0 = (swz & 15) * 256;   // 16 col tiles

  // staging: region 256 rows x 32 k; thread t -> row t>>2, 16B chunk t&3,
  // chunk XOR-swizzled via pre-swizzled GLOBAL source (LDS dest linear).
  const int rs = tid >> 2;                                  // 0..127
  const int ks = ((tid & 3) ^ ((tid >> 3) & 3)) * 8;        // swizzled k-elem off
  const unsigned short* Ar0 = A + (size_t)(m0 + rs) * D + ks;
  const unsigned short* Ar1 = Ar0 + (size_t)128 * D;
  const unsigned short* Br0 = B + (size_t)(n0 + rs) * D + ks;
  const unsigned short* Br1 = Br0 + (size_t)128 * D;
  char* ldst = smem + tid * 16;

  // frag-read byte offsets within a region (row*64B + swizzled 16B chunk)
  const int swz16 = (((lane >> 4) ^ ((lane >> 1) & 3)) << 4);
  const int aRd = (wr * 128 + (lane & 15)) * 64 + swz16;    // + fm*1024 + region
  const int bRd = (wc * 64 + (lane & 15)) * 64 + swz16;     // + fn*1024 + region

#define STAGE(p, kt) do {                                            \
    const int _ab = (p) * 16384;                                     \
    const int _bb = 49152 + (p) * 16384;                             \
    const int _ko = (kt) * 32;                                       \
    gload_lds16(Ar0 + _ko, ldst + _ab);                              \
    gload_lds16(Ar1 + _ko, ldst + _ab + 8192);                       \
    gload_lds16(Br0 + _ko, ldst + _bb);                              \
    gload_lds16(Br1 + _ko, ldst + _bb + 8192);                       \
  } while (0)

#define READ12(xa, xb, rbase) do {                                   \
    _Pragma("unroll")                                                \
    for (int fm = 0; fm < 8; ++fm)                                   \
      xa[fm] = *(const bf16x8*)(smem + (rbase) * 16384 + aRd + fm * 1024); \
    _Pragma("unroll")                                                \
    for (int fn = 0; fn < 4; ++fn)                                   \
      xb[fn] = *(const bf16x8*)(smem + 49152 + (rbase) * 16384 + bRd + fn * 1024); \
  } while (0)

#define MFMA32(xa, xb) do {                                          \
    _Pragma("unroll")                                                \
    for (int fm = 0; fm < 8; ++fm)                                   \
      _Pragma("unroll")                                              \
      for (int fn = 0; fn < 4; ++fn)                                 \
        acc[fm][fn] = MFMA(xa[fm], xb[fn], acc[fm][fn]);             \
    __builtin_amdgcn_s_setprio(0);                                   \
  } while (0)

// one K-step: single scheduling region {12 ds_read | 32 MFMA | 4 gload},
// interleave enforced by sched_group_barrier pattern (DS=0x100, MFMA=0x8,
// VMEM=0x10). Compiler inserts counted lgkmcnt for operand deps itself.
#define SUBSTEP(cxa, cxb, nxa, nxb) do {                             \
    WAIT_VM(4);                      /* publish region rp's stage */ \
    ASM_BAR();                                                       \
    READ12(nxa, nxb, rp);                                            \
    MFMA32(cxa, cxb);                                                \
    STAGE(sp, kst);                                                  \
    _Pragma("unroll")                                                \
    for (int i = 0; i < 12; ++i) { SGB(0x100, 1, 0); SGB(0x8, 2, 0); } \
    _Pragma("unroll")                                                \
    for (int i = 0; i < 4; ++i)  { SGB(0x10, 1, 0);  SGB(0x8, 2, 0); } \
    rp = (rp == 2) ? 0 : rp + 1;                                     \
    sp = (sp == 2) ? 0 : sp + 1;                                     \
    kst = (kst < 127) ? kst + 1 : 127;                               \
  } while (0)

  f32x4 acc[8][4] = {};
  bf16x8 ca[8], na[8];
  bf16x8 cb[4], nb[4];

  // ---- prologue: stage k0,k1,k2 into regions 0,1,2; read step-0 operands
  STAGE(0, 0);
  STAGE(1, 1);
  STAGE(2, 2);
  WAIT_VM(8);          // region 0 retired
  ASM_BAR();
  READ12(ca, cb, 0);

  int rp = 1, sp = 0, kst = 3;
  for (int d = 0; d < 64; ++d) {
    SUBSTEP(ca, cb, na, nb);
    SUBSTEP(na, nb, ca, cb);
  }
#undef SUBSTEP
#undef MFMA32
#undef READ12
#undef STAGE

  // ---- epilogue: C/D layout col=lane&15, row=(lane>>4)*4+i ----
  const int orow = (lane >> 4) * 4;
  const int ocol = lane & 15;
  float* Cw = C + (size_t)(m0 + wr * 128 + orow) * D + n0 + wc * 64 + ocol;
#pragma unroll
  for (int fm = 0; fm < 8; ++fm)
#pragma unroll
    for (int fn = 0; fn < 4; ++fn)
#pragma unroll
      for (int i = 0; i < 4; ++i)
        Cw[(size_t)(fm * 16 + i) * D + fn * 16] = acc[fm][fn][i];
}

extern "C" void kernel_launch(void* const* d_in, const int* in_sizes, int n_in,
                              void* d_out, int out_size, void* d_ws, size_t ws_size,
                              hipStream_t stream) {
  const float* x = (const float*)d_in[0];   // [4,4096,4096] fp32
  const float* w = (const float*)d_in[1];   // [4096,4096] fp32
  float* out = (float*)d_out;               // [16384,4096] fp32

  char* ws = (char*)d_ws;
  double* wn_d = (double*)ws;                                   // 32 KB
  float* wn_f = (float*)(ws + 32768);                           // 16 KB
  unsigned short* wbf = (unsigned short*)(ws + 49152);          // 33.5 MB
  unsigned short* xsb = (unsigned short*)(ws + 49152 + (size_t)D * D * 2);  // 134 MB

  hipMemsetAsync(wn_d, 0, D * sizeof(double), stream);
  k_wnorm<<<dim3(16, 16), 256, 0, stream>>>(w, wn_d, wbf);
  k_wnf<<<16, 256, 0, stream>>>(wn_d, wn_f);
  k_prune<<<M, 256, 0, stream>>>(x, wn_f, xsb);
  k_gemm<<<dim3((M / 256) * (D / 256)), 512, 98304, stream>>>(xsb, wbf, out);
}